// Round 1
// baseline (3829.596 us; speedup 1.0000x reference)
//
#include <hip/hip_runtime.h>
#include <math.h>

// Causal attention forward, fp32 baseline.
// Q: [B, L, H, E], K: [B, S, H, E], V: [B, S, H, D], out: [B, L, H, D]
// B=2, L=S=2048, H=16, E=D=64. scale = 1/8.

constexpr int BB = 2, LL = 2048, HH = 16, EE = 64;
constexpr int SS = LL, DD = 64;
constexpr float SCALE = 0.125f;

__global__ __launch_bounds__(256) void attn_fwd_f32(
    const float* __restrict__ Q, const float* __restrict__ K,
    const float* __restrict__ V, float* __restrict__ Out)
{
    // K tile transposed: kT[e][s] with row stride 65 (pad +1) -> conflict-free
    __shared__ float kT[64 * 65];
    __shared__ float p_s[4][64];

    const int tid  = threadIdx.x;
    const int wv   = tid >> 6;    // wave in block, 0..3
    const int lane = tid & 63;

    const int blocksPerBH = LL / 4;
    const int bh    = blockIdx.x / blocksPerBH;
    const int lbase = (blockIdx.x % blocksPerBH) * 4;
    const int b = bh / HH, h = bh % HH;
    const int l = lbase + wv;     // this wave's query row

    const size_t qoff = (((size_t)b * LL + l) * HH + h) * (size_t)EE;

    // q row into registers (all lanes same address -> broadcast, 1 line per load)
    float qr[64];
    {
        const float4* q4 = (const float4*)(Q + qoff);
        #pragma unroll
        for (int i = 0; i < 16; ++i) {
            float4 v = q4[i];
            qr[4*i+0] = v.x; qr[4*i+1] = v.y; qr[4*i+2] = v.z; qr[4*i+3] = v.w;
        }
    }

    // base offset of (b, s=0, h) in K/V; step per key = HH*64 floats
    const size_t kvbase = ((size_t)b * SS * HH + (size_t)h) * 64;
    const int    kstep  = HH * 64;  // 1024 floats between consecutive keys

    float m = -INFINITY, lsum = 0.f, acc = 0.f;

    const int ntiles = lbase / 64 + 1;  // same for all 4 waves in block
    for (int t = 0; t < ntiles; ++t) {
        const int s0 = t * 64;

        // ---- cooperative stage: 64 keys x 64 channels, transposed into kT ----
        // iter it: rows s0 + it*4 + wv, channel = lane (coalesced global read)
        #pragma unroll
        for (int it = 0; it < 16; ++it) {
            int si = it * 4 + wv;
            kT[lane * 65 + si] = K[kvbase + (size_t)(s0 + si) * kstep + lane];
        }
        __syncthreads();

        // ---- phase A: lane = key index, score = q . k ----
        float sc = 0.f;
        #pragma unroll
        for (int e = 0; e < 64; ++e)
            sc = fmaf(qr[e], kT[e * 65 + lane], sc);

        const int s = s0 + lane;
        sc = (s <= l) ? sc * SCALE : -INFINITY;

        // wave-wide online softmax
        float mt = sc;
        #pragma unroll
        for (int off = 32; off; off >>= 1)
            mt = fmaxf(mt, __shfl_xor(mt, off, 64));
        const float newm = fmaxf(m, mt);
        const float corr = __expf(m - newm);       // m=-inf first tile -> 0
        const float p    = __expf(sc - newm);      // masked -> exp(-inf)=0
        float psum = p;
        #pragma unroll
        for (int off = 32; off; off >>= 1)
            psum += __shfl_xor(psum, off, 64);
        lsum = lsum * corr + psum;
        m = newm;
        p_s[wv][lane] = p;

        // ---- phase B: lane = output channel d, acc += sum_i p[i]*V[s0+i][d] ----
        acc *= corr;
        const float* vb = V + kvbase + (size_t)s0 * kstep + lane;
        #pragma unroll
        for (int i4 = 0; i4 < 16; ++i4) {
            float4 p4 = *(const float4*)&p_s[wv][i4 * 4];   // broadcast read
            acc = fmaf(p4.x, vb[(size_t)(i4*4+0) * kstep], acc);
            acc = fmaf(p4.y, vb[(size_t)(i4*4+1) * kstep], acc);
            acc = fmaf(p4.z, vb[(size_t)(i4*4+2) * kstep], acc);
            acc = fmaf(p4.w, vb[(size_t)(i4*4+3) * kstep], acc);
        }
        __syncthreads();   // all waves done with kT before restage
    }

    Out[qoff + lane] = acc / lsum;
}

extern "C" void kernel_launch(void* const* d_in, const int* in_sizes, int n_in,
                              void* d_out, int out_size, void* d_ws, size_t ws_size,
                              hipStream_t stream) {
    const float* Q = (const float*)d_in[0];
    const float* K = (const float*)d_in[1];
    const float* V = (const float*)d_in[2];
    float* out = (float*)d_out;
    (void)in_sizes; (void)n_in; (void)out_size; (void)d_ws; (void)ws_size;

    dim3 grid(BB * HH * (LL / 4));   // 16384 blocks; consecutive blocks share (b,h)
    attn_fwd_f32<<<grid, 256, 0, stream>>>(Q, K, V, out);
}

// Round 2
// 164.643 us; speedup vs baseline: 23.2599x; 23.2599x over previous
//
#include <hip/hip_runtime.h>
#include <math.h>

// Causal flash attention fwd, bf16 MFMA. fp32 in/out.
// Q:[B,L,H,E] K:[B,S,H,E] V:[B,S,H,D] Out:[B,L,H,D]; B=2,L=S=2048,H=16,E=D=64.

constexpr int BB = 2, LL = 2048, HH = 16;
constexpr int SS = LL;
constexpr float SCALE = 0.125f;
constexpr int QB = 64;      // query rows per block (4 waves x 16)
constexpr int KVB = 64;     // keys per tile
constexpr float NEG = -1e30f;

using bf16x8 = __attribute__((ext_vector_type(8))) short;
using f32x4  = __attribute__((ext_vector_type(4))) float;

__device__ inline unsigned short f2bf(float f) {
    unsigned u = __builtin_bit_cast(unsigned, f);
    return (unsigned short)((u + 0x7fffu + ((u >> 16) & 1u)) >> 16);
}

__global__ void attn_mfma(const float* __restrict__ Q, const float* __restrict__ K,
                          const float* __restrict__ V, float* __restrict__ Out)
{
    // K tile [key][e] bf16, 128B rows, granule-swizzled by (row&7)
    __shared__ __align__(16) short Kb[64 * 64];
    // V tile transposed [d][k] bf16, 128B rows, granule-swizzled by G3(d)
    __shared__ __align__(16) short Vt[64 * 64];
    // per-wave P tile [row16][key64] bf16
    __shared__ __align__(16) short Pl[4][16 * 64];

    const int tid  = threadIdx.x;
    const int wv   = tid >> 6;
    const int lane = tid & 63;
    const int g    = lane >> 4;   // quarter-wave group
    const int c16  = lane & 15;

    // largest-work blocks first: bh fast index, q-tile desc as slow index
    const int bh = blockIdx.x & 31;           // b*16 + h
    const int qi = 31 - (blockIdx.x >> 5);    // descending
    const int b = bh >> 4, h = bh & 15;
    const int q0  = qi * QB;
    const int wq0 = q0 + wv * 16;             // this wave's first row

    const size_t kvbase = ((size_t)b * SS * HH + h) * 64;
    const int kstep = HH * 64;                // floats between consecutive keys

    // ---- Q fragments (A-layout: row=lane&15, k=(lane>>4)*8+j), bf16 ----
    bf16x8 aQ[2];
    {
        const int l = wq0 + c16;
        const float* qp = Q + ((size_t)(b * LL + l) * HH + h) * 64 + g * 8;
        #pragma unroll
        for (int ks = 0; ks < 2; ++ks) {
            float4 f0 = *(const float4*)(qp + ks * 32);
            float4 f1 = *(const float4*)(qp + ks * 32 + 4);
            bf16x8 a;
            a[0] = f2bf(f0.x); a[1] = f2bf(f0.y); a[2] = f2bf(f0.z); a[3] = f2bf(f0.w);
            a[4] = f2bf(f1.x); a[5] = f2bf(f1.y); a[6] = f2bf(f1.z); a[7] = f2bf(f1.w);
            aQ[ks] = a;
        }
    }

    f32x4 Oacc[4];
    #pragma unroll
    for (int dt = 0; dt < 4; ++dt) Oacc[dt] = (f32x4){0.f, 0.f, 0.f, 0.f};
    float m[4]    = {NEG, NEG, NEG, NEG};
    float lsum[4] = {0.f, 0.f, 0.f, 0.f};

    const int ntiles = q0 / KVB + 1;
    for (int t = 0; t < ntiles; ++t) {
        const int s0 = t * KVB;

        // ---- stage K (row-major) and V (transposed), fp32->bf16 ----
        #pragma unroll
        for (int it = 0; it < 4; ++it) {
            const int idx = it * 256 + tid;
            const int row = idx >> 4;      // key within tile
            const int c4  = idx & 15;      // float4 within row
            const float* gsrc = K + kvbase + (size_t)(s0 + row) * kstep + c4 * 4;
            float4 kf = *(const float4*)gsrc;
            short4 kp;
            kp.x = (short)f2bf(kf.x); kp.y = (short)f2bf(kf.y);
            kp.z = (short)f2bf(kf.z); kp.w = (short)f2bf(kf.w);
            const int kb = row * 128 + ((c4 * 8) ^ ((row & 7) << 4));
            *(short4*)((char*)Kb + kb) = kp;

            const float* gv = V + kvbase + (size_t)(s0 + row) * kstep + c4 * 4;
            float4 vf = *(const float4*)gv;
            unsigned short vb[4] = {f2bf(vf.x), f2bf(vf.y), f2bf(vf.z), f2bf(vf.w)};
            #pragma unroll
            for (int i = 0; i < 4; ++i) {
                const int d  = c4 * 4 + i;
                const int gr = (((d & 3) << 1) ^ (d >> 2)) & 7;
                const int vb_off = d * 128 + ((row * 2) ^ (gr << 4));
                *(short*)((char*)Vt + vb_off) = (short)vb[i];
            }
        }
        __syncthreads();

        if (s0 <= wq0 + 15) {   // wave has unmasked keys in this tile
            // ---- S = Q . K^T  (4 col-tiles x 2 k-steps) ----
            f32x4 Sv[4];
            #pragma unroll
            for (int nt = 0; nt < 4; ++nt) {
                f32x4 acc = (f32x4){0.f, 0.f, 0.f, 0.f};
                #pragma unroll
                for (int ks = 0; ks < 2; ++ks) {
                    const int row = nt * 16 + c16;           // key index
                    const int off = row * 128 + (((ks * 32 + g * 8) * 2) ^ ((row & 7) << 4));
                    bf16x8 bk = *(const bf16x8*)((char*)Kb + off);
                    acc = __builtin_amdgcn_mfma_f32_16x16x32_bf16(aQ[ks], bk, acc, 0, 0, 0);
                }
                Sv[nt] = acc;
            }

            // ---- online softmax per row (row = g*4+reg over 16-lane group) ----
            float corr[4];
            #pragma unroll
            for (int reg = 0; reg < 4; ++reg) {
                const int lrow = wq0 + g * 4 + reg;
                float sv[4];
                float mt = NEG;
                #pragma unroll
                for (int nt = 0; nt < 4; ++nt) {
                    const int skey = s0 + nt * 16 + c16;
                    float x = Sv[nt][reg] * SCALE;
                    x = (skey <= lrow) ? x : NEG;
                    sv[nt] = x;
                    mt = fmaxf(mt, x);
                }
                #pragma unroll
                for (int off = 1; off < 16; off <<= 1)
                    mt = fmaxf(mt, __shfl_xor(mt, off, 64));
                const float nm = fmaxf(m[reg], mt);
                const float c  = __expf(m[reg] - nm);
                m[reg] = nm; corr[reg] = c;
                float ps = 0.f;
                unsigned short pb[4];
                #pragma unroll
                for (int nt = 0; nt < 4; ++nt) {
                    float p = __expf(sv[nt] - nm);
                    ps += p;
                    pb[nt] = f2bf(p);
                }
                #pragma unroll
                for (int off = 1; off < 16; off <<= 1)
                    ps += __shfl_xor(ps, off, 64);
                lsum[reg] = lsum[reg] * c + ps;
                // write P row to per-wave LDS (A-frag layout source)
                const int prow = g * 4 + reg;
                #pragma unroll
                for (int nt = 0; nt < 4; ++nt) {
                    const int col = nt * 16 + c16;
                    const int off = prow * 128 + ((col * 2) ^ ((prow & 7) << 4));
                    *(short*)((char*)(&Pl[wv][0]) + off) = (short)pb[nt];
                }
            }

            // ---- rescale O ----
            #pragma unroll
            for (int dt = 0; dt < 4; ++dt)
                #pragma unroll
                for (int reg = 0; reg < 4; ++reg) Oacc[dt][reg] *= corr[reg];

            // ---- O += P . V ----
            #pragma unroll
            for (int ks = 0; ks < 2; ++ks) {
                const int prow = c16;
                const int poff = prow * 128 + (((ks * 32 + g * 8) * 2) ^ ((prow & 7) << 4));
                bf16x8 pa = *(const bf16x8*)((char*)(&Pl[wv][0]) + poff);
                #pragma unroll
                for (int dt = 0; dt < 4; ++dt) {
                    const int d  = dt * 16 + c16;
                    const int gr = (((d & 3) << 1) ^ (d >> 2)) & 7;
                    const int voff = d * 128 + (((ks * 32 + g * 8) * 2) ^ (gr << 4));
                    bf16x8 bv = *(const bf16x8*)((char*)Vt + voff);
                    Oacc[dt] = __builtin_amdgcn_mfma_f32_16x16x32_bf16(pa, bv, Oacc[dt], 0, 0, 0);
                }
            }
        }
        __syncthreads();
    }

    // ---- epilogue: O / lsum ----
    #pragma unroll
    for (int reg = 0; reg < 4; ++reg) {
        const float inv = 1.0f / lsum[reg];
        const int l = wq0 + g * 4 + reg;
        float* op = Out + ((size_t)(b * LL + l) * HH + h) * 64 + c16;
        #pragma unroll
        for (int dt = 0; dt < 4; ++dt)
            op[dt * 16] = Oacc[dt][reg] * inv;
    }
}

extern "C" void kernel_launch(void* const* d_in, const int* in_sizes, int n_in,
                              void* d_out, int out_size, void* d_ws, size_t ws_size,
                              hipStream_t stream) {
    const float* Q = (const float*)d_in[0];
    const float* K = (const float*)d_in[1];
    const float* V = (const float*)d_in[2];
    float* out = (float*)d_out;
    (void)in_sizes; (void)n_in; (void)out_size; (void)d_ws; (void)ws_size;

    dim3 grid((LL / QB) * BB * HH);   // 1024 blocks
    attn_mfma<<<grid, 256, 0, stream>>>(Q, K, V, out);
}

// Round 4
// 133.349 us; speedup vs baseline: 28.7185x; 1.2347x over previous
//
#include <hip/hip_runtime.h>

// Causal flash attention fwd, bf16 MFMA, swapped-QK layout. fp32 in/out.
// Q:[B,L,H,E] K:[B,S,H,E] V:[B,S,H,D] Out:[B,L,H,D]; B=2,L=S=2048,H=16,E=D=64.

constexpr int BB = 2, LL = 2048, HH = 16;
constexpr int SS = LL;
constexpr float SL2E = 0.125f * 1.44269504088896340736f;  // scale * log2(e)
constexpr int QB = 64;     // q rows per block (4 waves x 16)
constexpr int KVB = 128;   // keys per tile
constexpr float NEG = -1e30f;
constexpr int VSTR = 136;  // Vt row stride in shorts (272B, 16B-aligned)

using bf16x8 = __attribute__((ext_vector_type(8))) short;
using f32x4  = __attribute__((ext_vector_type(4))) float;

__device__ inline float fast_exp2(float x) { return __builtin_amdgcn_exp2f(x); }

__device__ inline unsigned short f2bf(float f) {
    unsigned u = __builtin_bit_cast(unsigned, f);
    return (unsigned short)((u + 0x7fffu + ((u >> 16) & 1u)) >> 16);
}
__device__ inline unsigned pk2(float lo, float hi) {
    return (unsigned)f2bf(lo) | ((unsigned)f2bf(hi) << 16);
}

__global__ __launch_bounds__(256, 4) void attn_swap(
    const float* __restrict__ Q, const float* __restrict__ K,
    const float* __restrict__ V, float* __restrict__ Out)
{
    __shared__ __align__(16) short Kb[KVB * 64];   // [key][e], XOR-swizzled 128B rows
    __shared__ __align__(16) short Vt[64 * VSTR];  // [d][k-slot], padded stride

    const int tid  = threadIdx.x;
    const int wv   = tid >> 6;
    const int lane = tid & 63;
    const int g    = lane >> 4;
    const int c16  = lane & 15;

    const int bh = blockIdx.x & 31;
    const int qi = 31 - (blockIdx.x >> 5);    // heaviest q-tiles first
    const int b = bh >> 4, h = bh & 15;
    const int q0  = qi * QB;
    const int wq0 = q0 + wv * 16;
    const int qrow = wq0 + c16;               // this lane's softmax row

    const size_t kvbase = ((size_t)b * SS * HH + h) * 64;
    const int kstep = HH * 64;

    // ---- Q B-fragments: B[e-octet g][n=qrow=c16] ----
    bf16x8 bQ[2];
    {
        const float* qp = Q + ((size_t)(b * LL + qrow) * HH + h) * 64 + g * 8;
        #pragma unroll
        for (int es = 0; es < 2; ++es) {
            float4 f0 = *(const float4*)(qp + es * 32);
            float4 f1 = *(const float4*)(qp + es * 32 + 4);
            bf16x8 a;
            a[0] = f2bf(f0.x); a[1] = f2bf(f0.y); a[2] = f2bf(f0.z); a[3] = f2bf(f0.w);
            a[4] = f2bf(f1.x); a[5] = f2bf(f1.y); a[6] = f2bf(f1.z); a[7] = f2bf(f1.w);
            bQ[es] = a;
        }
    }

    // ---- staging precompute ----
    const int krow0 = tid >> 4;        // K: row krow0+16*it, quad
    const int kquad = tid & 15;
    const float* pK = K + kvbase + (size_t)krow0 * kstep + kquad * 4;
    const int kb0 = krow0 * 128 + ((kquad * 8) ^ ((krow0 & 7) << 4));

    const int vrow0 = wv * 4 + g;      // V: row vrow0+16*it, float4 at c16
    const float* pV = V + kvbase + (size_t)vrow0 * kstep + c16 * 4;
    const int dv = c16 * 4 + g;        // d row owned after 4x4 transpose

    f32x4 Oacc[4];
    #pragma unroll
    for (int dt = 0; dt < 4; ++dt) Oacc[dt] = (f32x4){0.f, 0.f, 0.f, 0.f};
    float m = NEG, lsum = 0.f;

    const int ntiles = (q0 + 191) >> 7;
    for (int t = 0; t < ntiles; ++t) {
        const int s0 = t << 7;

        // ---- stage K: fp32->bf16, swizzled row-major ----
        #pragma unroll
        for (int it = 0; it < 8; ++it) {
            float4 kf = *(const float4*)(pK + (size_t)it * 16 * kstep);
            short4 kp;
            kp.x = (short)f2bf(kf.x); kp.y = (short)f2bf(kf.y);
            kp.z = (short)f2bf(kf.z); kp.w = (short)f2bf(kf.w);
            *(short4*)((char*)Kb + (kb0 + it * 2048)) = kp;
        }
        // ---- stage V: fp32->bf16, 4x4 lane transpose, slot-permuted rows ----
        #pragma unroll
        for (int it = 0; it < 8; ++it) {
            float4 vf = *(const float4*)(pV + (size_t)it * 16 * kstep);
            unsigned short a0 = f2bf(vf.x), a1 = f2bf(vf.y),
                           a2 = f2bf(vf.z), a3 = f2bf(vf.w);
            // stage 1: xor 16 (g bit0)
            unsigned s1 = (g & 1) ? ((unsigned)a0 | ((unsigned)a2 << 16))
                                  : ((unsigned)a1 | ((unsigned)a3 << 16));
            unsigned r1 = __shfl_xor(s1, 16, 64);
            if (g & 1) { a0 = (unsigned short)r1; a2 = (unsigned short)(r1 >> 16); }
            else       { a1 = (unsigned short)r1; a3 = (unsigned short)(r1 >> 16); }
            // stage 2: xor 32 (g bit1)
            unsigned s2 = (g & 2) ? ((unsigned)a0 | ((unsigned)a1 << 16))
                                  : ((unsigned)a2 | ((unsigned)a3 << 16));
            unsigned r2 = __shfl_xor(s2, 32, 64);
            if (g & 2) { a0 = (unsigned short)r2; a1 = (unsigned short)(r2 >> 16); }
            else       { a2 = (unsigned short)r2; a3 = (unsigned short)(r2 >> 16); }
            // tau(r0): bit-swap puts key r0+j at PV-consumption slot
            const int tau = 32 * (it >> 1) + 4 * (it & 1) + 8 * wv;
            short4 vw; vw.x = (short)a0; vw.y = (short)a1; vw.z = (short)a2; vw.w = (short)a3;
            *(short4*)((char*)Vt + ((dv * VSTR) + tau) * 2) = vw;
        }
        pK += (size_t)128 * kstep;
        pV += (size_t)128 * kstep;
        __syncthreads();

        if (s0 <= wq0 + 15) {
            // ---- S^T = K . Q^T : D[key][qrow], 8 key-tiles x 2 e-steps ----
            f32x4 Sv[8];
            #pragma unroll
            for (int kt = 0; kt < 8; ++kt) {
                f32x4 acc = (f32x4){0.f, 0.f, 0.f, 0.f};
                const int krow = kt * 16 + c16;
                #pragma unroll
                for (int es = 0; es < 2; ++es) {
                    const int off = krow * 128 + (((es * 64) + g * 16) ^ ((krow & 7) << 4));
                    bf16x8 aK = *(const bf16x8*)((char*)Kb + off);
                    acc = __builtin_amdgcn_mfma_f32_16x16x32_bf16(aK, bQ[es], acc, 0, 0, 0);
                }
                Sv[kt] = acc;
            }

            // ---- scale (+ mask on diagonal tiles), tile max ----
            const bool full = (s0 + 127 <= wq0);
            const int thresh = qrow - s0;     // key_local <= thresh is valid
            float mx = NEG;
            #pragma unroll
            for (int kt = 0; kt < 8; ++kt) {
                #pragma unroll
                for (int r = 0; r < 4; ++r) {
                    float x = Sv[kt][r] * SL2E;
                    if (!full) x = (kt * 16 + g * 4 + r <= thresh) ? x : NEG;
                    Sv[kt][r] = x;
                    mx = fmaxf(mx, x);
                }
            }
            mx = fmaxf(mx, __shfl_xor(mx, 16, 64));
            mx = fmaxf(mx, __shfl_xor(mx, 32, 64));

            // ---- online softmax state (scalar per lane), defer-max ----
            const float nm = fmaxf(m, mx);
            if (!__all(nm - m <= 8.0f)) {
                const float corr = fast_exp2(m - nm);
                lsum *= corr;
                m = nm;
                #pragma unroll
                for (int r = 0; r < 4; ++r) {
                    const float cr = __shfl(corr, g * 4 + r, 64);
                    #pragma unroll
                    for (int dt = 0; dt < 4; ++dt) Oacc[dt][r] *= cr;
                }
            }

            // ---- p = 2^(x-m), pack bf16; A-frags are lane-local via V slot-permute ----
            float ps = 0.f;
            unsigned pb[16];
            #pragma unroll
            for (int kt = 0; kt < 8; ++kt) {
                const float p0 = fast_exp2(Sv[kt][0] - m);
                const float p1 = fast_exp2(Sv[kt][1] - m);
                const float p2 = fast_exp2(Sv[kt][2] - m);
                const float p3 = fast_exp2(Sv[kt][3] - m);
                ps += (p0 + p1) + (p2 + p3);
                pb[kt * 2]     = pk2(p0, p1);
                pb[kt * 2 + 1] = pk2(p2, p3);
            }
            ps += __shfl_xor(ps, 16, 64);
            ps += __shfl_xor(ps, 32, 64);
            lsum += ps;

            // ---- O += P . V ----
            #pragma unroll
            for (int ks = 0; ks < 4; ++ks) {
                uint4 pu; pu.x = pb[4 * ks]; pu.y = pb[4 * ks + 1];
                pu.z = pb[4 * ks + 2]; pu.w = pb[4 * ks + 3];
                const bf16x8 pa = __builtin_bit_cast(bf16x8, pu);
                #pragma unroll
                for (int dt = 0; dt < 4; ++dt) {
                    const int voff = ((dt * 16 + c16) * VSTR + 32 * ks + 8 * g) * 2;
                    bf16x8 bV = *(const bf16x8*)((char*)Vt + voff);
                    Oacc[dt] = __builtin_amdgcn_mfma_f32_16x16x32_bf16(pa, bV, Oacc[dt], 0, 0, 0);
                }
            }
        }
        __syncthreads();
    }

    // ---- epilogue: rows g*4+r, divide by that row's lsum ----
    #pragma unroll
    for (int r = 0; r < 4; ++r) {
        const float ls = __shfl(lsum, g * 4 + r, 64);
        const float inv = 1.0f / ls;
        const int orow = wq0 + g * 4 + r;
        float* op = Out + ((size_t)(b * LL + orow) * HH + h) * 64 + c16;
        #pragma unroll
        for (int dt = 0; dt < 4; ++dt)
            op[dt * 16] = Oacc[dt][r] * inv;
    }
}

extern "C" void kernel_launch(void* const* d_in, const int* in_sizes, int n_in,
                              void* d_out, int out_size, void* d_ws, size_t ws_size,
                              hipStream_t stream) {
    const float* Q = (const float*)d_in[0];
    const float* K = (const float*)d_in[1];
    const float* V = (const float*)d_in[2];
    float* out = (float*)d_out;
    (void)in_sizes; (void)n_in; (void)out_size; (void)d_ws; (void)ws_size;

    dim3 grid((LL / QB) * BB * HH);   // 1024 blocks, heavy tiles first
    attn_swap<<<grid, 256, 0, stream>>>(Q, K, V, out);
}